// Round 2
// baseline (422.360 us; speedup 1.0000x reference)
//
#include <hip/hip_runtime.h>

typedef unsigned short u16;
typedef __attribute__((ext_vector_type(8))) short bf16x8;
typedef __attribute__((ext_vector_type(4))) float f32x4;

#define MFMA16(a, b, c) __builtin_amdgcn_mfma_f32_16x16x32_bf16(a, b, c, 0, 0, 0)

__device__ __forceinline__ u16 f2bf(float f) {
  union { float f; unsigned u; } v; v.f = f;
  unsigned r = v.u + 0x7fffu + ((v.u >> 16) & 1u);
  return (u16)(r >> 16);
}

__device__ __forceinline__ unsigned pkbf(float lo, float hi) {
  unsigned r;
  asm("v_cvt_pk_bf16_f32 %0, %1, %2" : "=v"(r) : "v"(lo), "v"(hi));
  return r;
}

// In-register transpose: input a[t][r] = M[row = t*16 + g*4 + r][col = li] (f32),
// output: lane holds bf16 M[g*8+j][li], j=0..7  (i.e. column li of rows 0..31,
// chunked 8-consecutive-rows per 16-lane group) — the A/B-fragment layout.
__device__ __forceinline__ bf16x8 xform(const float* a0, const float* a1, int srcA, bool hi) {
  unsigned p0 = pkbf(a0[0], a0[1]), p1 = pkbf(a0[2], a0[3]);
  unsigned p2 = pkbf(a1[0], a1[1]), p3 = pkbf(a1[2], a1[3]);
  int srcB = srcA + 16;
  unsigned u0 = __shfl((int)p0, srcA), u1 = __shfl((int)p1, srcA);
  unsigned u2 = __shfl((int)p2, srcA), u3 = __shfl((int)p3, srcA);
  unsigned v0 = __shfl((int)p0, srcB), v1 = __shfl((int)p1, srcB);
  unsigned v2 = __shfl((int)p2, srcB), v3 = __shfl((int)p3, srcB);
  union { bf16x8 v; unsigned w[4]; } o;
  o.w[0] = hi ? u2 : u0; o.w[1] = hi ? u3 : u1;
  o.w[2] = hi ? v2 : v0; o.w[3] = hi ? v3 : v1;
  return o.v;
}

// ---------------- pack: weights -> bf16 fragment layout, bias table -> bias_full ----
// wpack  [36 ntiles][6 ks][64 lane][8]  from wqkv_w[192][576]
// wppack [12 ntiles][6 ks][64 lane][8]  from wp_w[192][192]
// bias_full[6][64][64]                  from bias_table[225][6]
__global__ void pack_kernel(const float* __restrict__ wqkv_w,
                            const float* __restrict__ wp_w,
                            const float* __restrict__ bias_table,
                            u16* __restrict__ wpack, u16* __restrict__ wppack,
                            float* __restrict__ bias_full) {
  int i = blockIdx.x * 256 + threadIdx.x;
  if (i < 110592) {
    int j = i & 7, l = (i >> 3) & 63;
    int rest = i >> 9;
    int ks = rest % 6, nt = rest / 6;
    int k = ks * 32 + (l >> 4) * 8 + j;
    int n = nt * 16 + (l & 15);
    wpack[i] = f2bf(wqkv_w[k * 576 + n]);
  } else if (i < 147456) {
    int i2 = i - 110592;
    int j = i2 & 7, l = (i2 >> 3) & 63;
    int rest = i2 >> 9;
    int ks = rest % 6, nt = rest / 6;
    int k = ks * 32 + (l >> 4) * 8 + j;
    int n = nt * 16 + (l & 15);
    wppack[i2] = f2bf(wp_w[k * 192 + n]);
  } else if (i < 172032) {
    int i2 = i - 147456;
    int kk = i2 & 63, q = (i2 >> 6) & 63, h = i2 >> 12;
    int r1 = q >> 3, c1 = q & 7, r2 = kk >> 3, c2 = kk & 7;
    int idx = (r1 - r2 + 7) * 15 + (c1 - c2 + 7);
    bias_full[i2] = bias_table[idx * 6 + h];
  }
}

// ---------------- fused window qkv + attention (register-resident) ----------------
// 1 block = 1 window (64 tokens); 6 waves = 6 heads. Only LDS: x fragments (24.6 KB).
__global__ __launch_bounds__(384, 3) void win_attn(
    const float* __restrict__ x, const u16* __restrict__ wpack,
    const float* __restrict__ wqkv_b, const float* __restrict__ bias_full,
    u16* __restrict__ y) {
  __shared__ u16 xs[12288];          // [4 mt][6 ks][64 lane][8]
  const int tid = threadIdx.x;
  const int lane = tid & 63;
  const int wv = tid >> 6;           // head
  const int g = lane >> 4, li = lane & 15;
  const int blk = blockIdx.x;
  const int bb = blk / 576, rem = blk % 576, wy = rem / 24, wx = rem % 24;
  const size_t xbase = (size_t)bb * 36864;

  // ---- stage x window into LDS as bf16 A-fragments ----
  {
    const int tk = tid / 6, part = tid - (tid / 6) * 6;   // token, 32-col part (=ks)
    const int rr = tk >> 3, cc = tk & 7;
    const float* xrow = x + (xbase + (wy * 8 + rr) * 192 + wx * 8 + cc) * 192 + part * 32;
    const int mt0 = tk >> 4, li0 = tk & 15;
    u16* dst = xs + ((mt0 * 6 + part) * 64 + li0) * 8;
    float4 f[8];
#pragma unroll
    for (int it = 0; it < 8; ++it) f[it] = ((const float4*)xrow)[it];
#pragma unroll
    for (int g2 = 0; g2 < 4; ++g2) {
      union { bf16x8 v; unsigned w[4]; } o;
      o.w[0] = pkbf(f[g2 * 2].x, f[g2 * 2].y);
      o.w[1] = pkbf(f[g2 * 2].z, f[g2 * 2].w);
      o.w[2] = pkbf(f[g2 * 2 + 1].x, f[g2 * 2 + 1].y);
      o.w[3] = pkbf(f[g2 * 2 + 1].z, f[g2 * 2 + 1].w);
      *(bf16x8*)(dst + g2 * 128) = o.v;
    }
  }
  __syncthreads();

  const float scale = 0.17677669529663687f;   // 1/sqrt(32)
  const f32x4 zero4 = {0.f, 0.f, 0.f, 0.f};
  const int srcA = (lane & 16) * 2 + li;      // ((g&1)*2)*16 + li
  const bool hi = lane >= 32;
  const u16* wbase = wpack + lane * 8;

  // ---- phase 1a: Q^T, K^T = mfma(W_frag, x_frag) ----
  f32x4 qt[2][4], kt[2][4];
#pragma unroll
  for (int i = 0; i < 2; ++i)
#pragma unroll
    for (int mt = 0; mt < 4; ++mt) { qt[i][mt] = zero4; kt[i][mt] = zero4; }
#pragma unroll
  for (int ks = 0; ks < 6; ++ks) {
    bf16x8 af[4];
#pragma unroll
    for (int mt = 0; mt < 4; ++mt)
      af[mt] = *(const bf16x8*)(xs + ((mt * 6 + ks) * 64 + lane) * 8);
#pragma unroll
    for (int i = 0; i < 2; ++i) {
      bf16x8 wq = *(const bf16x8*)(wbase + ((2 * wv + i) * 6 + ks) * 512);
      bf16x8 wk = *(const bf16x8*)(wbase + ((12 + 2 * wv + i) * 6 + ks) * 512);
#pragma unroll
      for (int mt = 0; mt < 4; ++mt) {
        qt[i][mt] = MFMA16(wq, af[mt], qt[i][mt]);
        kt[i][mt] = MFMA16(wk, af[mt], kt[i][mt]);
      }
    }
  }

  // pack Q (scaled, +bias) and K (+bias) into S-operand fragments
  float bqa[2][4], bka[2][4];
#pragma unroll
  for (int i = 0; i < 2; ++i) {
    float4 t1 = *(const float4*)(wqkv_b + wv * 32 + i * 16 + g * 4);
    bqa[i][0] = t1.x; bqa[i][1] = t1.y; bqa[i][2] = t1.z; bqa[i][3] = t1.w;
    float4 t2 = *(const float4*)(wqkv_b + 192 + wv * 32 + i * 16 + g * 4);
    bka[i][0] = t2.x; bka[i][1] = t2.y; bka[i][2] = t2.z; bka[i][3] = t2.w;
  }
  bf16x8 qf[4], kf[4];
#pragma unroll
  for (int mt = 0; mt < 4; ++mt) {
    float a0[4], a1[4];
#pragma unroll
    for (int r = 0; r < 4; ++r) {
      a0[r] = (qt[0][mt][r] + bqa[0][r]) * scale;
      a1[r] = (qt[1][mt][r] + bqa[1][r]) * scale;
    }
    qf[mt] = xform(a0, a1, srcA, hi);
#pragma unroll
    for (int r = 0; r < 4; ++r) {
      a0[r] = kt[0][mt][r] + bka[0][r];
      a1[r] = kt[1][mt][r] + bka[1][r];
    }
    kf[mt] = xform(a0, a1, srcA, hi);
  }

  // ---- phase 1b: V = mfma(x_frag, Wv_frag) ----
  f32x4 va[4][2];
#pragma unroll
  for (int mt = 0; mt < 4; ++mt) { va[mt][0] = zero4; va[mt][1] = zero4; }
#pragma unroll
  for (int ks = 0; ks < 6; ++ks) {
    bf16x8 af[4];
#pragma unroll
    for (int mt = 0; mt < 4; ++mt)
      af[mt] = *(const bf16x8*)(xs + ((mt * 6 + ks) * 64 + lane) * 8);
    bf16x8 wv0 = *(const bf16x8*)(wbase + ((24 + 2 * wv) * 6 + ks) * 512);
    bf16x8 wv1 = *(const bf16x8*)(wbase + ((25 + 2 * wv) * 6 + ks) * 512);
#pragma unroll
    for (int mt = 0; mt < 4; ++mt) {
      va[mt][0] = MFMA16(af[mt], wv0, va[mt][0]);
      va[mt][1] = MFMA16(af[mt], wv1, va[mt][1]);
    }
  }
  float bva[2] = { wqkv_b[384 + wv * 32 + li], wqkv_b[384 + wv * 32 + 16 + li] };
  bf16x8 vf[2][2];    // [d-tile i][key-chunk ks2]
#pragma unroll
  for (int i = 0; i < 2; ++i)
#pragma unroll
    for (int ks2 = 0; ks2 < 2; ++ks2) {
      float a0[4], a1[4];
#pragma unroll
      for (int r = 0; r < 4; ++r) {
        a0[r] = va[ks2 * 2][i][r] + bva[i];
        a1[r] = va[ks2 * 2 + 1][i][r] + bva[i];
      }
      vf[i][ks2] = xform(a0, a1, srcA, hi);
    }

  // ---- S^T = mfma(K, Q): lane holds S[q=nt*16+li][key=mt*16+g*4+r] ----
  f32x4 st[4][4];
#pragma unroll
  for (int mt = 0; mt < 4; ++mt)
#pragma unroll
    for (int nt = 0; nt < 4; ++nt) st[mt][nt] = MFMA16(kf[mt], qf[nt], zero4);

  // ---- softmax (row q per lane-quad) + P-frags + Y = P V ----
  const float* bfh = bias_full + wv * 4096 + li * 64 + g * 4;
  f32x4 yacc[4][2];
#pragma unroll
  for (int nt = 0; nt < 4; ++nt) { yacc[nt][0] = zero4; yacc[nt][1] = zero4; }
#pragma unroll
  for (int nt = 0; nt < 4; ++nt) {
    float e[4][4];
    float mx = -1e30f;
#pragma unroll
    for (int mt = 0; mt < 4; ++mt) {
      float4 b4 = *(const float4*)(bfh + nt * 1024 + mt * 16);
      e[mt][0] = st[mt][nt][0] + b4.x;
      e[mt][1] = st[mt][nt][1] + b4.y;
      e[mt][2] = st[mt][nt][2] + b4.z;
      e[mt][3] = st[mt][nt][3] + b4.w;
      mx = fmaxf(mx, fmaxf(fmaxf(e[mt][0], e[mt][1]), fmaxf(e[mt][2], e[mt][3])));
    }
    mx = fmaxf(mx, __shfl_xor(mx, 16));
    mx = fmaxf(mx, __shfl_xor(mx, 32));
    float s = 0.f;
#pragma unroll
    for (int mt = 0; mt < 4; ++mt)
#pragma unroll
      for (int r = 0; r < 4; ++r) { e[mt][r] = __expf(e[mt][r] - mx); s += e[mt][r]; }
    s += __shfl_xor(s, 16);
    s += __shfl_xor(s, 32);
    float inv = 1.0f / s;
#pragma unroll
    for (int ks2 = 0; ks2 < 2; ++ks2) {
      float a0[4], a1[4];
#pragma unroll
      for (int r = 0; r < 4; ++r) {
        a0[r] = e[ks2 * 2][r] * inv;
        a1[r] = e[ks2 * 2 + 1][r] * inv;
      }
      bf16x8 pf = xform(a0, a1, srcA, hi);
      yacc[nt][0] = MFMA16(pf, vf[0][ks2], yacc[nt][0]);
      yacc[nt][1] = MFMA16(pf, vf[1][ks2], yacc[nt][1]);
    }
  }

  // ---- store y (bf16, linear [b, H*W, c]): lane holds Y[q=nt*16+g*4+r][d=i*16+li] ----
#pragma unroll
  for (int nt = 0; nt < 4; ++nt)
#pragma unroll
    for (int r = 0; r < 4; ++r) {
      int tok = nt * 16 + g * 4 + r;
      size_t base = (xbase + (wy * 8 + (tok >> 3)) * 192 + wx * 8 + (tok & 7)) * 192 + wv * 32 + li;
      y[base] = f2bf(yacc[nt][0][r]);
      y[base + 16] = f2bf(yacc[nt][1][r]);
    }
}

// ---------------- projection GEMM: out = y @ wp + b (no LDS) ----------------
__global__ __launch_bounds__(256, 3) void proj_kernel(
    const u16* __restrict__ y, const u16* __restrict__ wppack,
    const float* __restrict__ wp_b, float* __restrict__ out) {
  const int tid = threadIdx.x;
  const int lane = tid & 63, wv = tid >> 6;
  const int g = lane >> 4, li = lane & 15;
  const size_t row0 = (size_t)blockIdx.x * 128 + wv * 32;
  const f32x4 zero4 = {0.f, 0.f, 0.f, 0.f};
  f32x4 acc[2][12];
#pragma unroll
  for (int mt = 0; mt < 2; ++mt)
#pragma unroll
    for (int nt = 0; nt < 12; ++nt) acc[mt][nt] = zero4;
#pragma unroll
  for (int ks = 0; ks < 6; ++ks) {
    bf16x8 af[2];
#pragma unroll
    for (int mt = 0; mt < 2; ++mt)
      af[mt] = *(const bf16x8*)(y + (row0 + mt * 16 + li) * 192 + ks * 32 + g * 8);
#pragma unroll
    for (int nt = 0; nt < 12; ++nt) {
      bf16x8 bf = *(const bf16x8*)(wppack + (nt * 6 + ks) * 512 + lane * 8);
      acc[0][nt] = MFMA16(af[0], bf, acc[0][nt]);
      acc[1][nt] = MFMA16(af[1], bf, acc[1][nt]);
    }
  }
#pragma unroll
  for (int nt = 0; nt < 12; ++nt) {
    float bb = wp_b[nt * 16 + li];
#pragma unroll
    for (int mt = 0; mt < 2; ++mt)
#pragma unroll
      for (int r = 0; r < 4; ++r)
        out[(row0 + mt * 16 + g * 4 + r) * 192 + nt * 16 + li] = acc[mt][nt][r] + bb;
  }
}

extern "C" void kernel_launch(void* const* d_in, const int* in_sizes, int n_in,
                              void* d_out, int out_size, void* d_ws, size_t ws_size,
                              hipStream_t stream) {
  (void)in_sizes; (void)n_in; (void)out_size; (void)ws_size;
  const float* x          = (const float*)d_in[0];
  const float* wqkv_w     = (const float*)d_in[1];
  const float* wqkv_b     = (const float*)d_in[2];
  const float* wp_w       = (const float*)d_in[3];
  const float* wp_b       = (const float*)d_in[4];
  const float* bias_table = (const float*)d_in[5];
  float* out = (float*)d_out;
  char* ws = (char*)d_ws;
  u16* wpack       = (u16*)(ws);              // 221184 B
  u16* wppack      = (u16*)(ws + 221184);     //  73728 B
  float* bias_full = (float*)(ws + 294912);   //  98304 B
  u16* y           = (u16*)(ws + 393216);     // 113246208 B

  pack_kernel<<<672, 256, 0, stream>>>(wqkv_w, wp_w, bias_table, wpack, wppack, bias_full);
  win_attn<<<4608, 384, 0, stream>>>(x, wpack, wqkv_b, bias_full, y);
  proj_kernel<<<2304, 256, 0, stream>>>(y, wppack, wp_b, out);
}